// Round 9
// baseline (106.765 us; speedup 1.0000x reference)
//
#include <hip/hip_runtime.h>

// SparseConv1D on MI355X, round 16 — CLEAN-COUNTER DIAGNOSTIC (intentional 2x sconv).
// R15 post-mortem: spill fixed, but core-first stage + split epilogue = exact null (89.32).
// Decomposition locked: 60us fixed floor + ~30us sconv across SIX structural rewrites.
// Pipe model (MFMA 19.9k, LDS ~15k, W-L1 ~16k, VALU ~8k cyc/block) predicts ~15us with
// overlap; measured 72k cyc/block looks near-SERIAL, and the real sconv has NEVER shown
// clean counters (always under the 44us top-5 cutoff; R11's were spill-polluted).
// R16: grid 512 = 256 real blocks + 256 shadow blocks (recompute id-256, write to d_ws
// scratch at +1MB). 128KB LDS => 1 block/CU => two serial rounds at TRUE occupancy; code
// path byte-identical (output base = wave-uniform SGPR select). sconv ~60us => top-5 with
// clean MfmaUtil/VALUBusy/FETCH/WRITE/conflicts.
// Pre-committed: MfmaUtil>=50% -> MFMA-bound, near-ceiling; VALUBusy>=35% -> stage VALU,
// revert to DMA staging; both low -> waitcnt serialization, attack with T19 clustering.
// FETCH ~130MB -> halo overfetch real; ~70MB -> L2 absorbs.

#define B_    16
#define CIN   64
#define COUT  64
#define LEN   4096
#define NTAP  32

typedef float f32x4 __attribute__((ext_vector_type(4)));
typedef short bf16x8_s __attribute__((ext_vector_type(8)));
typedef __bf16 bf16x8_b __attribute__((ext_vector_type(8)));

template <typename V>
static __device__ inline auto mfma_16x16x32_bf16(V a, V b, f32x4 c, int)
    -> decltype(__builtin_amdgcn_mfma_f32_16x16x32_bf16(a, b, c, 0, 0, 0)) {
  return __builtin_amdgcn_mfma_f32_16x16x32_bf16(a, b, c, 0, 0, 0);
}
template <typename V>
static __device__ inline f32x4 mfma_16x16x32_bf16(V a, V b, f32x4 c, long) {
  return __builtin_amdgcn_mfma_f32_16x16x32_bf16(
      __builtin_bit_cast(bf16x8_b, a), __builtin_bit_cast(bf16x8_b, b), c, 0, 0, 0);
}

static __device__ inline unsigned short f32_to_bf16_rne(float f) {
  unsigned int u = __builtin_bit_cast(unsigned int, f);
  u += 0x7fffu + ((u >> 16) & 1u);
  return (unsigned short)(u >> 16);
}

// ---- prep_w: w[o][i][t] f32 -> Wf[t][c][m][lane][8] bf16 (frag-major, 8KB/tap) ----
__global__ __launch_bounds__(256) void prep_w(const float* __restrict__ w,
                                              unsigned short* __restrict__ wf) {
  const int base = blockIdx.x * 1024;          // grid 128 -> 131072 elems
#pragma unroll
  for (int it = 0; it < 4; ++it) {
    const int e = base + it * 256 + threadIdx.x;
    const int j = e & 7;
    const int lane = (e >> 3) & 63;
    const int m = (e >> 9) & 3;
    const int c = (e >> 11) & 1;
    const int t = e >> 12;
    const int o = m * 16 + (lane & 15);
    const int i = c * 32 + (lane >> 4) * 8 + j;
    wf[e] = f32_to_bf16_rne(w[(size_t)(o * CIN + i) * NTAP + t]);
  }
}

// ------- main: R15 structure + shadow blocks for clean counters ------------------------
__global__ __launch_bounds__(512, 2) void sconv_main(const float* __restrict__ x,
                                                     const unsigned short* __restrict__ wf,
                                                     float* __restrict__ out,
                                                     float* __restrict__ shadow) {
  constexpr int TAP[NTAP] = {-512, -256, -128, -96, -64, -48, -32, -24, -16, -12, -8,
                             -6,   -4,   -3,   -2,  -1,  0,   1,   2,   3,   4,  6,
                             8,    12,   16,   24,  32,  48,  64,  96,  128, 256};
  // central taps (windows within phase-1 rows [-64,320)) first, then far taps
  constexpr int ORD[NTAP] = {10, 11, 12, 13, 14, 15, 16, 17, 18, 19, 20, 21, 22,
                             0,  1,  2,  3,  4,  5,  6,  7,  8,  9,
                             23, 24, 25, 26, 27, 28, 29, 30, 31};
  // phase-2 stage chunks (64 rows each), issued during taps j=0..9
  constexpr int P2[10] = {-128, -192, -256, -320, -384, -448, -512, 320, 384, 448};
  __shared__ alignas(16) char smem[131072];   // ring: 1024 rows x 128B

  const int id = blockIdx.x;                  // 512 blocks: [0,256) real, [256,512) shadow
  const int rid = id & 255;                   // work identity (b, l0) of the real block
  const int b = (rid & 7) * 2 + (rid >> 7);   // XCD k <- batches {2k,2k+1}
  const int l0 = ((rid >> 3) & 15) * 256;     // 16 l-tiles of 256
  const int lb = l0 + 512;                    // ring-phase base (mult of 256)
  float* const obase = (id < 256) ? out : shadow;  // wave-uniform SGPR select, no spill
  const int tid = threadIdx.x;
  const int wv = tid >> 6, lane = tid & 63;
  const int q = lane >> 4, r = lane & 15;
  const int lh = wv >> 1, ch = wv & 1;        // wave: l-quarter (64 l), i-half (32 i)

  const char* wbase = (const char*)wf;
  const float* xb = x + (size_t)b * CIN * LEN;

  // stage one [64 l][64 i] chunk at window rows [lc, lc+64): f32 -> bf16 -> swizzled ring.
  auto stage_iter = [&](int lc) {
    const int h = lane & 7;
    const int i0 = 16 * (wv & 3) + 2 * h;
    const int row0 = lc + ((wv >> 2) << 5) + ((lane >> 3) << 2);
    const int gl = l0 + row0;                  // global l of the 4-quad (mult of 4)
    f32x4 va = {0.f, 0.f, 0.f, 0.f}, vb = {0.f, 0.f, 0.f, 0.f};
    if ((unsigned)gl < (unsigned)LEN) {
      va = *(const f32x4*)&xb[(size_t)i0 * LEN + gl];
      vb = *(const f32x4*)&xb[(size_t)(i0 + 1) * LEN + gl];
    }
#pragma unroll
    for (int j = 0; j < 4; ++j) {
      const unsigned u = (unsigned)f32_to_bf16_rne(va[j]) |
                         ((unsigned)f32_to_bf16_rne(vb[j]) << 16);
      const int slot = (lb + row0 + j) & 1023;
      const int cs = (i0 >> 3) ^ (slot & 7);
      *(unsigned*)(smem + slot * 128 + (cs << 4) + (i0 & 7) * 2) = u;
    }
  };

  bf16x8_s Wreg[2][4], Breg[2][4];
  f32x4 acc[4][4] = {};

  auto loadW = [&](int tt, int p) {            // global, frag-major, coalesced, L2-hit
    const char* src = wbase + tt * 8192 + ch * 4096 + lane * 16;
#pragma unroll
    for (int m = 0; m < 4; ++m)
      Wreg[p][m] = *(const bf16x8_s*)(src + m * 1024);
  };
  // slot&7 == (TAP+r)&7 (lb, lh*64, 16n all 0 mod 8) -> same involution as the write side
  auto readB = [&](int tt, int p) {
    const int e = (TAP[tt] + r) & 7;
#pragma unroll
    for (int n = 0; n < 4; ++n) {
      const int slot = (lb + TAP[tt] + lh * 64 + 16 * n + r) & 1023;
      Breg[p][n] = *(const bf16x8_s*)(smem + slot * 128 + (((ch * 4 + q) ^ e) << 4));
    }
  };

  // ---- phase-1 stage: CORE first (rows [0,256)), then [256,320) and [-64,0) ----
  loadW(ORD[0], 0);
  stage_iter(0);
  stage_iter(64);
  stage_iter(128);
  stage_iter(192);
  stage_iter(256);
  stage_iter(-64);
  __syncthreads();                             // phase-1 rows resident
  readB(ORD[0], 0);

  // ---- tap loop, permuted order; phase-2 halo staged under taps 0..9 ----
#pragma unroll
  for (int j = 0; j < NTAP; ++j) {
    const int p = j & 1;
    if (j == 13) {
      __syncthreads();                         // phase-2 rows resident (writes issued j<=9)
      readB(ORD[13], p);                       // no prefetch lead across the barrier
    }
    if (j + 1 < NTAP) {
      loadW(ORD[j + 1], p ^ 1);                // vmcnt-counted, 2-deep dbuf
      if (j != 12) readB(ORD[j + 1], p ^ 1);   // lgkmcnt-counted (skip across barrier)
    }
    __builtin_amdgcn_sched_barrier(0);         // pin prefetch issue above this tap's MFMAs
#pragma unroll
    for (int m = 0; m < 4; ++m)
#pragma unroll
      for (int n = 0; n < 4; ++n)
        acc[m][n] = mfma_16x16x32_bf16(Wreg[p][m], Breg[p][n], acc[m][n], 0);
    __builtin_amdgcn_sched_barrier(0);         // keep stage below the MFMAs
    if (j < 10) stage_iter(P2[j]);             // halo chunk: L2-hit, hidden under pipe drain
  }

  // ---- split epilogue, ALL acc indices static (rule #20) ----
  __syncthreads();
  if (ch == 0) {
#pragma unroll
    for (int n = 0; n < 4; ++n) {
      *(f32x4*)(smem + lh * 32768 + 16384 + ((0 * 4 + n) * 64 + lane) * 16) = acc[2][n];
      *(f32x4*)(smem + lh * 32768 + 16384 + ((1 * 4 + n) * 64 + lane) * 16) = acc[3][n];
    }
  } else {
#pragma unroll
    for (int n = 0; n < 4; ++n) {
      *(f32x4*)(smem + lh * 32768 + ((0 * 4 + n) * 64 + lane) * 16) = acc[0][n];
      *(f32x4*)(smem + lh * 32768 + ((1 * 4 + n) * 64 + lane) * 16) = acc[1][n];
    }
  }
  __syncthreads();
  // C/D layout (verified): col(l) = lane&15, row(o) = (lane>>4)*4 + reg
  if (ch == 0) {
#pragma unroll
    for (int n = 0; n < 4; ++n) {
      const f32x4 o0 = *(const f32x4*)(smem + lh * 32768 + ((0 * 4 + n) * 64 + lane) * 16);
      const f32x4 o1 = *(const f32x4*)(smem + lh * 32768 + ((1 * 4 + n) * 64 + lane) * 16);
      const f32x4 v0 = acc[0][n] + o0;
      const f32x4 v1 = acc[1][n] + o1;
      const int l = l0 + lh * 64 + 16 * n + r;
#pragma unroll
      for (int d = 0; d < 4; ++d) {
        obase[((size_t)b * COUT + (0 + 4 * q + d)) * LEN + l] = v0[d];
        obase[((size_t)b * COUT + (16 + 4 * q + d)) * LEN + l] = v1[d];
      }
    }
  } else {
#pragma unroll
    for (int n = 0; n < 4; ++n) {
      const f32x4 o2 = *(const f32x4*)(smem + lh * 32768 + 16384 + ((0 * 4 + n) * 64 + lane) * 16);
      const f32x4 o3 = *(const f32x4*)(smem + lh * 32768 + 16384 + ((1 * 4 + n) * 64 + lane) * 16);
      const f32x4 v2 = acc[2][n] + o2;
      const f32x4 v3 = acc[3][n] + o3;
      const int l = l0 + lh * 64 + 16 * n + r;
#pragma unroll
      for (int d = 0; d < 4; ++d) {
        obase[((size_t)b * COUT + (32 + 4 * q + d)) * LEN + l] = v2[d];
        obase[((size_t)b * COUT + (48 + 4 * q + d)) * LEN + l] = v3[d];
      }
    }
  }
}

extern "C" void kernel_launch(void* const* d_in, const int* in_sizes, int n_in,
                              void* d_out, int out_size, void* d_ws, size_t ws_size,
                              hipStream_t stream) {
  const float* x = (const float*)d_in[0];        // [16][64][4096]
  const float* w = (const float*)d_in[1];        // [64][64][32]
  float* out = (float*)d_out;                    // [16][64][4096]

  unsigned short* wfp = (unsigned short*)d_ws;                 // 256 KB frag-major W
  float* shadow = (float*)((char*)d_ws + (1 << 20));           // 16 MB shadow-out scratch

  prep_w<<<dim3(128), 256, 0, stream>>>(w, wfp);
  sconv_main<<<dim3(512), 512, 0, stream>>>(x, wfp, out, shadow);
}

// Round 10
// 90.144 us; speedup vs baseline: 1.1844x; 1.1844x over previous
//
#include <hip/hip_runtime.h>

// SparseConv1D on MI355X, round 17.
// out[b,o,l] = sum_{t,i} W[o,i,t] * x[b,i,l+tap_t] = 32 shifted GEMMs (MFMA 16x16x32 bf16).
// R17 vs R16 (clean counters: MfmaUtil 22%, VALUBusy 20%, FETCH 13.8MB (L2-resident),
// conflicts 1.5%, no spill => pre-committed branch "both low = issue serialization").
// Budget per block: MFMA 16.4k + W-L1 16k + VALU 14k + LDS 8k + stage 6k ~= 60k ~= the
// 67k measured => pipes run SERIALLY. Cause: the two sched_barrier(0) pins force strict
// [loads][16xMFMA] phases; 8 symmetric contention-locked waves all idle the matrix pipe
// during loads and idle TA/L1 during MFMAs (R12 worse = 2x W traffic; R13 null = latency
// was never it).
//  - REMOVED both sched_barrier(0) pins.
//  - T19 braid per tap: 4x {MFMA 4, VMEM_READ 1, DS_READ 1, VALU 6} sched_group_barrier
//    skeleton -> each wave's stream feeds matrix+TA+LDS+VALU pipes concurrently.
//    Legal: MFMA(j) uses resident regs; braided W/B(j+1) independent; counted waits keep
//    FIFO order (W(j+1) before stage(j) in vmcnt queue).
//  - Everything else byte-identical to R15 (core-first stage, ORD taps, static epilogue).

#define B_    16
#define CIN   64
#define COUT  64
#define LEN   4096
#define NTAP  32

typedef float f32x4 __attribute__((ext_vector_type(4)));
typedef short bf16x8_s __attribute__((ext_vector_type(8)));
typedef __bf16 bf16x8_b __attribute__((ext_vector_type(8)));

template <typename V>
static __device__ inline auto mfma_16x16x32_bf16(V a, V b, f32x4 c, int)
    -> decltype(__builtin_amdgcn_mfma_f32_16x16x32_bf16(a, b, c, 0, 0, 0)) {
  return __builtin_amdgcn_mfma_f32_16x16x32_bf16(a, b, c, 0, 0, 0);
}
template <typename V>
static __device__ inline f32x4 mfma_16x16x32_bf16(V a, V b, f32x4 c, long) {
  return __builtin_amdgcn_mfma_f32_16x16x32_bf16(
      __builtin_bit_cast(bf16x8_b, a), __builtin_bit_cast(bf16x8_b, b), c, 0, 0, 0);
}

static __device__ inline unsigned short f32_to_bf16_rne(float f) {
  unsigned int u = __builtin_bit_cast(unsigned int, f);
  u += 0x7fffu + ((u >> 16) & 1u);
  return (unsigned short)(u >> 16);
}

// ---- prep_w: w[o][i][t] f32 -> Wf[t][c][m][lane][8] bf16 (frag-major, 8KB/tap) ----
__global__ __launch_bounds__(256) void prep_w(const float* __restrict__ w,
                                              unsigned short* __restrict__ wf) {
  const int base = blockIdx.x * 1024;          // grid 128 -> 131072 elems
#pragma unroll
  for (int it = 0; it < 4; ++it) {
    const int e = base + it * 256 + threadIdx.x;
    const int j = e & 7;
    const int lane = (e >> 3) & 63;
    const int m = (e >> 9) & 3;
    const int c = (e >> 11) & 1;
    const int t = e >> 12;
    const int o = m * 16 + (lane & 15);
    const int i = c * 32 + (lane >> 4) * 8 + j;
    wf[e] = f32_to_bf16_rne(w[(size_t)(o * CIN + i) * NTAP + t]);
  }
}

// ------- main: core-first 2-phase stage, permuted taps, T19-braided tap loop -----------
__global__ __launch_bounds__(512, 2) void sconv_main(const float* __restrict__ x,
                                                     const unsigned short* __restrict__ wf,
                                                     float* __restrict__ out) {
  constexpr int TAP[NTAP] = {-512, -256, -128, -96, -64, -48, -32, -24, -16, -12, -8,
                             -6,   -4,   -3,   -2,  -1,  0,   1,   2,   3,   4,  6,
                             8,    12,   16,   24,  32,  48,  64,  96,  128, 256};
  // central taps (windows within phase-1 rows [-64,320)) first, then far taps
  constexpr int ORD[NTAP] = {10, 11, 12, 13, 14, 15, 16, 17, 18, 19, 20, 21, 22,
                             0,  1,  2,  3,  4,  5,  6,  7,  8,  9,
                             23, 24, 25, 26, 27, 28, 29, 30, 31};
  // phase-2 stage chunks (64 rows each), issued during taps j=0..9
  constexpr int P2[10] = {-128, -192, -256, -320, -384, -448, -512, 320, 384, 448};
  __shared__ alignas(16) char smem[131072];   // ring: 1024 rows x 128B

  const int id = blockIdx.x;                  // 256 blocks = 16 b x 16 l-tiles
  const int b = (id & 7) * 2 + (id >> 7);     // XCD k <- batches {2k,2k+1}
  const int l0 = ((id >> 3) & 15) * 256;      // 16 l-tiles of 256
  const int lb = l0 + 512;                    // ring-phase base (mult of 256)
  const int tid = threadIdx.x;
  const int wv = tid >> 6, lane = tid & 63;
  const int q = lane >> 4, r = lane & 15;
  const int lh = wv >> 1, ch = wv & 1;        // wave: l-quarter (64 l), i-half (32 i)

  const char* wbase = (const char*)wf;
  const float* xb = x + (size_t)b * CIN * LEN;

  // stage one [64 l][64 i] chunk at window rows [lc, lc+64): f32 -> bf16 -> swizzled ring.
  auto stage_iter = [&](int lc) {
    const int h = lane & 7;
    const int i0 = 16 * (wv & 3) + 2 * h;
    const int row0 = lc + ((wv >> 2) << 5) + ((lane >> 3) << 2);
    const int gl = l0 + row0;                  // global l of the 4-quad (mult of 4)
    f32x4 va = {0.f, 0.f, 0.f, 0.f}, vb = {0.f, 0.f, 0.f, 0.f};
    if ((unsigned)gl < (unsigned)LEN) {
      va = *(const f32x4*)&xb[(size_t)i0 * LEN + gl];
      vb = *(const f32x4*)&xb[(size_t)(i0 + 1) * LEN + gl];
    }
#pragma unroll
    for (int j = 0; j < 4; ++j) {
      const unsigned u = (unsigned)f32_to_bf16_rne(va[j]) |
                         ((unsigned)f32_to_bf16_rne(vb[j]) << 16);
      const int slot = (lb + row0 + j) & 1023;
      const int cs = (i0 >> 3) ^ (slot & 7);
      *(unsigned*)(smem + slot * 128 + (cs << 4) + (i0 & 7) * 2) = u;
    }
  };

  bf16x8_s Wreg[2][4], Breg[2][4];
  f32x4 acc[4][4] = {};

  auto loadW = [&](int tt, int p) {            // global, frag-major, coalesced, L2-hit
    const char* src = wbase + tt * 8192 + ch * 4096 + lane * 16;
#pragma unroll
    for (int m = 0; m < 4; ++m)
      Wreg[p][m] = *(const bf16x8_s*)(src + m * 1024);
  };
  // slot&7 == (TAP+r)&7 (lb, lh*64, 16n all 0 mod 8) -> same involution as the write side
  auto readB = [&](int tt, int p) {
    const int e = (TAP[tt] + r) & 7;
#pragma unroll
    for (int n = 0; n < 4; ++n) {
      const int slot = (lb + TAP[tt] + lh * 64 + 16 * n + r) & 1023;
      Breg[p][n] = *(const bf16x8_s*)(smem + slot * 128 + (((ch * 4 + q) ^ e) << 4));
    }
  };

  // ---- phase-1 stage: CORE first (rows [0,256)), then [256,320) and [-64,0) ----
  loadW(ORD[0], 0);
  stage_iter(0);
  stage_iter(64);
  stage_iter(128);
  stage_iter(192);
  stage_iter(256);
  stage_iter(-64);
  __syncthreads();                             // phase-1 rows resident
  readB(ORD[0], 0);

  // ---- tap loop, permuted order; phase-2 halo staged under taps 0..9; T19 braid ----
#pragma unroll
  for (int j = 0; j < NTAP; ++j) {
    const int p = j & 1;
    if (j == 13) {
      __syncthreads();                         // phase-2 rows resident (writes issued j<=9)
      readB(ORD[13], p);                       // no prefetch lead across the barrier
    }
    if (j + 1 < NTAP) {
      loadW(ORD[j + 1], p ^ 1);                // vmcnt-counted, 2-deep dbuf
      if (j != 12) readB(ORD[j + 1], p ^ 1);   // lgkmcnt-counted (skip across barrier)
    }
#pragma unroll
    for (int m = 0; m < 4; ++m)
#pragma unroll
      for (int n = 0; n < 4; ++n)
        acc[m][n] = mfma_16x16x32_bf16(Wreg[p][m], Breg[p][n], acc[m][n], 0);
    if (j < 10) stage_iter(P2[j]);             // halo chunk: L2-hit
    // T19 braid skeleton for this tap: interleave MFMA with VMEM/DS/VALU so the matrix
    // pipe, TA/L1 and LDS run CONCURRENTLY instead of phase-locked.
    // Masks (m137): VALU=0x2, MFMA=0x8, VMEM_READ=0x20, DS_READ=0x100.
#pragma unroll
    for (int k = 0; k < 4; ++k) {
      __builtin_amdgcn_sched_group_barrier(0x8, 4, 0);     // 4 MFMA
      __builtin_amdgcn_sched_group_barrier(0x20, 1, 0);    // 1 global load (W / stage)
      __builtin_amdgcn_sched_group_barrier(0x100, 1, 0);   // 1 ds_read (B)
      __builtin_amdgcn_sched_group_barrier(0x2, 6, 0);     // 6 VALU (addr / cvt)
    }
  }

  // ---- split epilogue, ALL acc indices static (rule #20) ----
  __syncthreads();
  if (ch == 0) {
#pragma unroll
    for (int n = 0; n < 4; ++n) {
      *(f32x4*)(smem + lh * 32768 + 16384 + ((0 * 4 + n) * 64 + lane) * 16) = acc[2][n];
      *(f32x4*)(smem + lh * 32768 + 16384 + ((1 * 4 + n) * 64 + lane) * 16) = acc[3][n];
    }
  } else {
#pragma unroll
    for (int n = 0; n < 4; ++n) {
      *(f32x4*)(smem + lh * 32768 + ((0 * 4 + n) * 64 + lane) * 16) = acc[0][n];
      *(f32x4*)(smem + lh * 32768 + ((1 * 4 + n) * 64 + lane) * 16) = acc[1][n];
    }
  }
  __syncthreads();
  // C/D layout (verified): col(l) = lane&15, row(o) = (lane>>4)*4 + reg
  if (ch == 0) {
#pragma unroll
    for (int n = 0; n < 4; ++n) {
      const f32x4 o0 = *(const f32x4*)(smem + lh * 32768 + ((0 * 4 + n) * 64 + lane) * 16);
      const f32x4 o1 = *(const f32x4*)(smem + lh * 32768 + ((1 * 4 + n) * 64 + lane) * 16);
      const f32x4 v0 = acc[0][n] + o0;
      const f32x4 v1 = acc[1][n] + o1;
      const int l = l0 + lh * 64 + 16 * n + r;
#pragma unroll
      for (int d = 0; d < 4; ++d) {
        out[((size_t)b * COUT + (0 + 4 * q + d)) * LEN + l] = v0[d];
        out[((size_t)b * COUT + (16 + 4 * q + d)) * LEN + l] = v1[d];
      }
    }
  } else {
#pragma unroll
    for (int n = 0; n < 4; ++n) {
      const f32x4 o2 = *(const f32x4*)(smem + lh * 32768 + 16384 + ((0 * 4 + n) * 64 + lane) * 16);
      const f32x4 o3 = *(const f32x4*)(smem + lh * 32768 + 16384 + ((1 * 4 + n) * 64 + lane) * 16);
      const f32x4 v2 = acc[2][n] + o2;
      const f32x4 v3 = acc[3][n] + o3;
      const int l = l0 + lh * 64 + 16 * n + r;
#pragma unroll
      for (int d = 0; d < 4; ++d) {
        out[((size_t)b * COUT + (32 + 4 * q + d)) * LEN + l] = v2[d];
        out[((size_t)b * COUT + (48 + 4 * q + d)) * LEN + l] = v3[d];
      }
    }
  }
}

extern "C" void kernel_launch(void* const* d_in, const int* in_sizes, int n_in,
                              void* d_out, int out_size, void* d_ws, size_t ws_size,
                              hipStream_t stream) {
  const float* x = (const float*)d_in[0];        // [16][64][4096]
  const float* w = (const float*)d_in[1];        // [64][64][32]
  float* out = (float*)d_out;                    // [16][64][4096]

  unsigned short* wfp = (unsigned short*)d_ws;   // 256 KB frag-major W

  prep_w<<<dim3(128), 256, 0, stream>>>(w, wfp);
  sconv_main<<<dim3(256), 512, 0, stream>>>(x, wfp, out);
}